// Round 16
// baseline (386.567 us; speedup 1.0000x reference)
//
#include <hip/hip_runtime.h>
#include <hip/hip_bf16.h>

typedef __attribute__((ext_vector_type(8))) short bf16x8;
typedef __attribute__((ext_vector_type(4))) float f32x4;

__device__ __forceinline__ ushort bf16rne(float f) {
    uint u = __float_as_uint(f);
    return (ushort)((u + 0x7fffu + ((u >> 16) & 1u)) >> 16);
}
__device__ __forceinline__ void unpack2(uint p, float& a, float& b) {
    a = __uint_as_float(p << 16);
    b = __uint_as_float(p & 0xffff0000u);
}

// ---------------- merged castT + bucket histogram ----------------

__global__ __launch_bounds__(256) void k_pre1(const float* __restrict__ W1,
                                              const float* __restrict__ Wm,
                                              const float* __restrict__ W2,
                                              ushort* __restrict__ w1t,
                                              ushort* __restrict__ wmt,
                                              ushort* __restrict__ w2t,
                                              const int* __restrict__ dst,
                                              int* __restrict__ bcnt, int E) {
    __shared__ int hist[512];
    int b = blockIdx.x;
    int t = threadIdx.x;
    if (b < 152) {
        if (b < 64) {
            int i = b * 256 + t; int k = i >> 7, n = i & 127;
            w1t[n * 128 + k] = bf16rne(W1[k * 128 + n]);
        } else if (b < 128) {
            int i = (b - 64) * 256 + t; int k = i >> 7, n = i & 127;
            wmt[n * 128 + k] = bf16rne(Wm[k * 128 + n]);
        } else {
            int i = (b - 128) * 256 + t;
            if (i < 6144) {
                int n = i >> 7, k = i & 127;
                w2t[n * 128 + k] = (n < 40) ? bf16rne(W2[k * 40 + n]) : (ushort)0;
            }
        }
        return;
    }
    hist[t] = 0; hist[t + 256] = 0;
    __syncthreads();
    int off = (b - 152) * 4096;
    int cnt = min(4096, E - off);
    for (int i = t; i < cnt; i += 256) atomicAdd(&hist[dst[off + i] >> 8], 1);
    __syncthreads();
    if (hist[t]) atomicAdd(&bcnt[t], hist[t]);
    if (hist[t + 256]) atomicAdd(&bcnt[t + 256], hist[t + 256]);
}

__global__ void k_bscan(const int* __restrict__ bcnt, int* __restrict__ bbase,
                        int* __restrict__ bcur, int nbuck) {
    __shared__ int s[512];
    int t = threadIdx.x;  // 512
    s[t] = (t < nbuck) ? bcnt[t] : 0;
    __syncthreads();
    for (int d = 1; d < 512; d <<= 1) {
        int u = (t >= d) ? s[t - d] : 0;
        __syncthreads();
        if (t >= d) s[t] += u;
        __syncthreads();
    }
    int excl = (t == 0) ? 0 : s[t - 1];
    bbase[t] = excl;
    if (t < nbuck) bcur[t] = excl;
    if (t == 511) bbase[512] = s[511];
}

// ---------------- merged binpack + layer-1 GEMM (unscaled output) ----------------

__global__ __launch_bounds__(256) void k_pack_gemm(const int* __restrict__ src,
                                                   const int* __restrict__ dst,
                                                   int* __restrict__ bcur,
                                                   uint* __restrict__ pairbuf,
                                                   int E, int nbuck, int ntile,
                                                   const float* __restrict__ A,
                                                   const ushort* __restrict__ Wt,
                                                   ushort* __restrict__ C, int M) {
    __shared__ int hist[512];
    __shared__ int scn[512];
    __shared__ int cur[512];
    __shared__ int gbase[512];
    __shared__ uint sorted[4096];
    int t = threadIdx.x;
    if ((int)blockIdx.x >= ntile) {
        // ---- gemm1 body (unscaled out) ----
        int blk = blockIdx.x - ntile;
        int wave = t >> 6, lane = t & 63;
        int m16 = lane & 15, quad = lane >> 4;
        int rowA = blk * 64 + wave * 16 + m16;
        int rA = min(rowA, M - 1);
        const float4* A4 = (const float4*)A;

        f32x4 acc[8];
#pragma unroll
        for (int i = 0; i < 8; i++) acc[i] = (f32x4){0.f, 0.f, 0.f, 0.f};
#pragma unroll
        for (int it = 0; it < 4; it++) {
            float4 f0 = A4[(size_t)rA * 32 + 8 * it + 2 * quad];
            float4 f1 = A4[(size_t)rA * 32 + 8 * it + 2 * quad + 1];
            bf16x8 af;
            af[0] = (short)bf16rne(f0.x); af[1] = (short)bf16rne(f0.y);
            af[2] = (short)bf16rne(f0.z); af[3] = (short)bf16rne(f0.w);
            af[4] = (short)bf16rne(f1.x); af[5] = (short)bf16rne(f1.y);
            af[6] = (short)bf16rne(f1.z); af[7] = (short)bf16rne(f1.w);
#pragma unroll
            for (int nt = 0; nt < 8; nt++) {
                bf16x8 bfr = *(const bf16x8*)(Wt + (size_t)(nt * 16 + m16) * 128 + it * 32 + quad * 8);
                acc[nt] = __builtin_amdgcn_mfma_f32_16x16x32_bf16(af, bfr, acc[nt], 0, 0, 0);
            }
        }
        int rowBase = blk * 64 + wave * 16 + quad * 4;
#pragma unroll
        for (int nt = 0; nt < 8; nt++) {
            int col = nt * 16 + m16;
#pragma unroll
            for (int r = 0; r < 4; r++) {
                int row = rowBase + r;
                if (row < M) C[(size_t)row * 128 + col] = bf16rne(acc[nt][r]);
            }
        }
        return;
    }
    // ---- binpack body ----
    int off = blockIdx.x * 4096;
    int cnt = min(4096, E - off);
    hist[t] = 0; hist[t + 256] = 0;
    __syncthreads();
    for (int i = t; i < cnt; i += 256) {
        int b = dst[off + i] >> 8;
        atomicAdd(&hist[b], 1);
    }
    __syncthreads();
    scn[t] = hist[t]; scn[t + 256] = hist[t + 256];
    __syncthreads();
    for (int d = 1; d < 256; d <<= 1) {
        int u0 = (t >= d) ? scn[t - d] : 0;
        int u1 = (t >= d) ? scn[256 + t - d] : 0;
        __syncthreads();
        if (t >= d) { scn[t] += u0; scn[256 + t] += u1; }
        __syncthreads();
    }
    int tot0 = scn[255];
    scn[256 + t] += tot0;
    __syncthreads();
    cur[t] = (t == 0) ? 0 : scn[t - 1];
    cur[t + 256] = scn[t + 255];
    if (t < nbuck && hist[t] > 0) gbase[t] = atomicAdd(&bcur[t], hist[t]);
    int t2 = t + 256;
    if (t2 < nbuck && hist[t2] > 0) gbase[t2] = atomicAdd(&bcur[t2], hist[t2]);
    __syncthreads();
    for (int i = t; i < cnt; i += 256) {
        int d = dst[off + i];
        int s = src[off + i];
        int b = d >> 8;
        int pos = atomicAdd(&cur[b], 1);
        sorted[pos] = ((uint)(d & 255) << 24) | (uint)s;
    }
    __syncthreads();
    int wid = t >> 6, lane = t & 63;
    for (int b = wid; b < nbuck; b += 4) {
        int n = hist[b];
        if (n == 0) continue;
        int ls = (b == 0) ? 0 : scn[b - 1];
        int gb = gbase[b];
        for (int j = lane; j < n; j += 64)
            pairbuf[gb + j] = sorted[ls + j];
    }
}

#define CSR_CAP 5632
__global__ __launch_bounds__(256) void k_csrbuild(const uint* __restrict__ pairbuf,
                                                  const int* __restrict__ bbase,
                                                  int* __restrict__ rowptr,
                                                  float* __restrict__ dinv,
                                                  int* __restrict__ csr,
                                                  int N, int nbuck) {
    __shared__ int lhist[256];
    __shared__ int scn[256];
    __shared__ int lcur[256];
    __shared__ int lcsr[CSR_CAP];
    int b = blockIdx.x;
    int base = b << 8;
    int nn = min(256, N - base);
    int lo = bbase[b], hi = bbase[b + 1];
    int cnt = hi - lo;
    int t = threadIdx.x;
    lhist[t] = 0;
    __syncthreads();
    for (int i = t; i < cnt; i += 256) atomicAdd(&lhist[pairbuf[lo + i] >> 24], 1);
    __syncthreads();
    int mydeg = lhist[t];
    scn[t] = mydeg;
    __syncthreads();
    for (int d = 1; d < 256; d <<= 1) {
        int u = (t >= d) ? scn[t - d] : 0;
        __syncthreads();
        if (t >= d) scn[t] += u;
        __syncthreads();
    }
    int excl = (t == 0) ? 0 : scn[t - 1];
    lcur[t] = excl;
    if (t < nn) {
        rowptr[base + t] = lo + excl;
        dinv[base + t] = rsqrtf((float)(mydeg + 1));  // +1 = self-loop
    }
    if (b == nbuck - 1 && t == 0) rowptr[N] = hi;
    __syncthreads();
    if (cnt <= CSR_CAP) {
        for (int i = t; i < cnt; i += 256) {
            uint p = pairbuf[lo + i];
            int pos = atomicAdd(&lcur[p >> 24], 1);
            lcsr[pos] = (int)(p & 0xFFFFFFu);
        }
        __syncthreads();
        for (int i = t; i < cnt; i += 256) csr[lo + i] = lcsr[i];
    } else {
        for (int i = t; i < cnt; i += 256) {
            uint p = pairbuf[lo + i];
            int pos = lo + atomicAdd(&lcur[p >> 24], 1);
            csr[pos] = (int)(p & 0xFFFFFFu);
        }
    }
}

// ---------------- standalone aggregation (R7 structure: max gather concurrency) ----------------
// 16 nodes/block x 16 lanes x uint4 (one 256B row per load inst), x4 edge
// unroll, no LDS, no barrier. EDGE_W=true: input UNSCALED -> per-edge dinv[s]
// (only layer 1). Output h = relu(dn*acc + bias), PLAIN bf16 (downstream GEMM
// applies the dinv[row] pre-scale for the next layer).

template <bool EDGE_W>
__device__ __forceinline__ void agg128_body(const ushort* __restrict__ g,
                                            const float* __restrict__ dinv,
                                            const int* __restrict__ rowptr,
                                            const int* __restrict__ csr,
                                            const float* __restrict__ bias,
                                            ushort* __restrict__ hout, int N) {
    int t = threadIdx.x;
    int grp = t >> 4;
    int l = t & 15;
    int node = blockIdx.x * 16 + grp;
    if (node >= N) return;
    const uint4* g16 = (const uint4*)g;
    float dn = dinv[node];
    float a[8];
    {
        uint4 p = g16[(size_t)node * 16 + l];
        float u, v;
        if (EDGE_W) {
            unpack2(p.x, u, v); a[0] = u * dn; a[1] = v * dn;
            unpack2(p.y, u, v); a[2] = u * dn; a[3] = v * dn;
            unpack2(p.z, u, v); a[4] = u * dn; a[5] = v * dn;
            unpack2(p.w, u, v); a[6] = u * dn; a[7] = v * dn;
        } else {
            unpack2(p.x, a[0], a[1]); unpack2(p.y, a[2], a[3]);
            unpack2(p.z, a[4], a[5]); unpack2(p.w, a[6], a[7]);
        }
    }
    int e0 = rowptr[node], e1 = rowptr[node + 1];
    int e = e0;
    for (; e + 4 <= e1; e += 4) {
        int s0 = csr[e], s1 = csr[e + 1], s2 = csr[e + 2], s3 = csr[e + 3];
        float w0 = 1.f, w1 = 1.f, w2 = 1.f, w3 = 1.f;
        if (EDGE_W) { w0 = dinv[s0]; w1 = dinv[s1]; w2 = dinv[s2]; w3 = dinv[s3]; }
        uint4 p0 = g16[(size_t)s0 * 16 + l];
        uint4 p1 = g16[(size_t)s1 * 16 + l];
        uint4 p2 = g16[(size_t)s2 * 16 + l];
        uint4 p3 = g16[(size_t)s3 * 16 + l];
        float u, v;
        if (EDGE_W) {
            unpack2(p0.x, u, v); a[0] += u * w0; a[1] += v * w0;
            unpack2(p0.y, u, v); a[2] += u * w0; a[3] += v * w0;
            unpack2(p0.z, u, v); a[4] += u * w0; a[5] += v * w0;
            unpack2(p0.w, u, v); a[6] += u * w0; a[7] += v * w0;
            unpack2(p1.x, u, v); a[0] += u * w1; a[1] += v * w1;
            unpack2(p1.y, u, v); a[2] += u * w1; a[3] += v * w1;
            unpack2(p1.z, u, v); a[4] += u * w1; a[5] += v * w1;
            unpack2(p1.w, u, v); a[6] += u * w1; a[7] += v * w1;
            unpack2(p2.x, u, v); a[0] += u * w2; a[1] += v * w2;
            unpack2(p2.y, u, v); a[2] += u * w2; a[3] += v * w2;
            unpack2(p2.z, u, v); a[4] += u * w2; a[5] += v * w2;
            unpack2(p2.w, u, v); a[6] += u * w2; a[7] += v * w2;
            unpack2(p3.x, u, v); a[0] += u * w3; a[1] += v * w3;
            unpack2(p3.y, u, v); a[2] += u * w3; a[3] += v * w3;
            unpack2(p3.z, u, v); a[4] += u * w3; a[5] += v * w3;
            unpack2(p3.w, u, v); a[6] += u * w3; a[7] += v * w3;
        } else {
            unpack2(p0.x, u, v); a[0] += u; a[1] += v;
            unpack2(p0.y, u, v); a[2] += u; a[3] += v;
            unpack2(p0.z, u, v); a[4] += u; a[5] += v;
            unpack2(p0.w, u, v); a[6] += u; a[7] += v;
            unpack2(p1.x, u, v); a[0] += u; a[1] += v;
            unpack2(p1.y, u, v); a[2] += u; a[3] += v;
            unpack2(p1.z, u, v); a[4] += u; a[5] += v;
            unpack2(p1.w, u, v); a[6] += u; a[7] += v;
            unpack2(p2.x, u, v); a[0] += u; a[1] += v;
            unpack2(p2.y, u, v); a[2] += u; a[3] += v;
            unpack2(p2.z, u, v); a[4] += u; a[5] += v;
            unpack2(p2.w, u, v); a[6] += u; a[7] += v;
            unpack2(p3.x, u, v); a[0] += u; a[1] += v;
            unpack2(p3.y, u, v); a[2] += u; a[3] += v;
            unpack2(p3.z, u, v); a[4] += u; a[5] += v;
            unpack2(p3.w, u, v); a[6] += u; a[7] += v;
        }
    }
    for (; e < e1; e++) {
        int s = csr[e];
        float w = EDGE_W ? dinv[s] : 1.f;
        uint4 p = g16[(size_t)s * 16 + l];
        float u, v;
        unpack2(p.x, u, v); a[0] += u * w; a[1] += v * w;
        unpack2(p.y, u, v); a[2] += u * w; a[3] += v * w;
        unpack2(p.z, u, v); a[4] += u * w; a[5] += v * w;
        unpack2(p.w, u, v); a[6] += u * w; a[7] += v * w;
    }
    float4 b0 = ((const float4*)bias)[2 * l];
    float4 b1 = ((const float4*)bias)[2 * l + 1];
    float o[8];
    o[0] = fmaxf(a[0] * dn + b0.x, 0.f); o[1] = fmaxf(a[1] * dn + b0.y, 0.f);
    o[2] = fmaxf(a[2] * dn + b0.z, 0.f); o[3] = fmaxf(a[3] * dn + b0.w, 0.f);
    o[4] = fmaxf(a[4] * dn + b1.x, 0.f); o[5] = fmaxf(a[5] * dn + b1.y, 0.f);
    o[6] = fmaxf(a[6] * dn + b1.z, 0.f); o[7] = fmaxf(a[7] * dn + b1.w, 0.f);
    uint4 q;
    q.x = (uint)bf16rne(o[0]) | ((uint)bf16rne(o[1]) << 16);
    q.y = (uint)bf16rne(o[2]) | ((uint)bf16rne(o[3]) << 16);
    q.z = (uint)bf16rne(o[4]) | ((uint)bf16rne(o[5]) << 16);
    q.w = (uint)bf16rne(o[6]) | ((uint)bf16rne(o[7]) << 16);
    ((uint4*)hout)[(size_t)node * 16 + l] = q;
}

__global__ __launch_bounds__(256) void k_aggA(const ushort* __restrict__ g,
                                              const float* __restrict__ dinv,
                                              const int* __restrict__ rowptr,
                                              const int* __restrict__ csr,
                                              const float* __restrict__ bias,
                                              ushort* __restrict__ hout, int N) {
    agg128_body<true>(g, dinv, rowptr, csr, bias, hout, N);   // unscaled in
}

__global__ __launch_bounds__(256) void k_aggB(const ushort* __restrict__ g,
                                              const float* __restrict__ dinv,
                                              const int* __restrict__ rowptr,
                                              const int* __restrict__ csr,
                                              const float* __restrict__ bias,
                                              ushort* __restrict__ hout, int N) {
    agg128_body<false>(g, dinv, rowptr, csr, bias, hout, N);  // pre-scaled in
}

// ---------------- standalone GEMMs: C = (h @ Wt) * dinv[row], bf16 ----------------
// NT=8 -> 128 cols; NT=3 -> 40 cols (w2t zero-padded to 48).

template <int NT>
__device__ __forceinline__ void gemm_body(const ushort* __restrict__ A,
                                          const ushort* __restrict__ Wt,
                                          const float* __restrict__ dinv,
                                          ushort* __restrict__ C, int M, int ccols) {
    int t = threadIdx.x;
    int wave = t >> 6, lane = t & 63;
    int m16 = lane & 15, quad = lane >> 4;
    int rowA = blockIdx.x * 64 + wave * 16 + m16;
    int rA = min(rowA, M - 1);

    f32x4 acc[NT];
#pragma unroll
    for (int i = 0; i < NT; i++) acc[i] = (f32x4){0.f, 0.f, 0.f, 0.f};
#pragma unroll
    for (int it = 0; it < 4; it++) {
        bf16x8 af = *(const bf16x8*)(A + (size_t)rA * 128 + it * 32 + quad * 8);
#pragma unroll
        for (int nt = 0; nt < NT; nt++) {
            bf16x8 bfr = *(const bf16x8*)(Wt + (size_t)(nt * 16 + m16) * 128 + it * 32 + quad * 8);
            acc[nt] = __builtin_amdgcn_mfma_f32_16x16x32_bf16(af, bfr, acc[nt], 0, 0, 0);
        }
    }
    int rowBase = blockIdx.x * 64 + wave * 16 + quad * 4;
    float dnv[4];
#pragma unroll
    for (int r = 0; r < 4; r++) dnv[r] = dinv[min(rowBase + r, M - 1)];
#pragma unroll
    for (int nt = 0; nt < NT; nt++) {
        int col = nt * 16 + m16;
        if (col >= ccols) continue;
#pragma unroll
        for (int r = 0; r < 4; r++) {
            int row = rowBase + r;
            if (row < M) C[(size_t)row * ccols + col] = bf16rne(acc[nt][r] * dnv[r]);
        }
    }
}

__global__ __launch_bounds__(256) void k_gemm128s(const ushort* __restrict__ A,
                                                  const ushort* __restrict__ Wt,
                                                  const float* __restrict__ dinv,
                                                  ushort* __restrict__ C, int M) {
    gemm_body<8>(A, Wt, dinv, C, M, 128);
}

__global__ __launch_bounds__(256) void k_gemm40s(const ushort* __restrict__ A,
                                                 const ushort* __restrict__ Wt,
                                                 const float* __restrict__ dinv,
                                                 ushort* __restrict__ C, int M) {
    gemm_body<3>(A, Wt, dinv, C, M, 40);
}

// ---------------- final aggregation over 40-col rows (pre-scaled g3) ----------------

__global__ __launch_bounds__(256) void k_agg40_b(const ushort* __restrict__ g3,
                                                 const float* __restrict__ dinv,
                                                 const int* __restrict__ rowptr,
                                                 const int* __restrict__ csr,
                                                 const float* __restrict__ bias,
                                                 float* __restrict__ out, int N) {
    int t = threadIdx.x;
    if (t >= 250) return;
    int grp = t / 10;
    int l = t - grp * 10;
    int node = blockIdx.x * 25 + grp;
    if (node >= N) return;
    const uint2* gp = (const uint2*)g3;
    float dn = dinv[node];
    float a0, a1, a2, a3;
    {
        uint2 p = gp[(size_t)node * 10 + l];
        unpack2(p.x, a0, a1);
        unpack2(p.y, a2, a3);
    }
    int e0 = rowptr[node], e1 = rowptr[node + 1];
    int e = e0;
    for (; e + 4 <= e1; e += 4) {
        int s0 = csr[e], s1 = csr[e + 1], s2 = csr[e + 2], s3 = csr[e + 3];
        uint2 p0 = gp[(size_t)s0 * 10 + l];
        uint2 p1 = gp[(size_t)s1 * 10 + l];
        uint2 p2 = gp[(size_t)s2 * 10 + l];
        uint2 p3 = gp[(size_t)s3 * 10 + l];
        float u, v;
        unpack2(p0.x, u, v); a0 += u; a1 += v;
        unpack2(p0.y, u, v); a2 += u; a3 += v;
        unpack2(p1.x, u, v); a0 += u; a1 += v;
        unpack2(p1.y, u, v); a2 += u; a3 += v;
        unpack2(p2.x, u, v); a0 += u; a1 += v;
        unpack2(p2.y, u, v); a2 += u; a3 += v;
        unpack2(p3.x, u, v); a0 += u; a1 += v;
        unpack2(p3.y, u, v); a2 += u; a3 += v;
    }
    for (; e < e1; e++) {
        int s = csr[e];
        uint2 p = gp[(size_t)s * 10 + l];
        float u, v;
        unpack2(p.x, u, v); a0 += u; a1 += v;
        unpack2(p.y, u, v); a2 += u; a3 += v;
    }
    float4 bb = ((const float4*)bias)[l];
    float4 o;
    o.x = a0 * dn + bb.x;
    o.y = a1 * dn + bb.y;
    o.z = a2 * dn + bb.z;
    o.w = a3 * dn + bb.w;
    ((float4*)out)[(size_t)node * 10 + l] = o;
}

// ---------------- launch ----------------

extern "C" void kernel_launch(void* const* d_in, const int* in_sizes, int n_in,
                              void* d_out, int out_size, void* d_ws, size_t ws_size,
                              hipStream_t stream) {
    const float* x  = (const float*)d_in[0];
    const int* eidx = (const int*)d_in[1];
    const float* W1 = (const float*)d_in[2];
    const float* b1 = (const float*)d_in[3];
    const float* Wm = (const float*)d_in[4];
    const float* bm = (const float*)d_in[5];
    const float* W2 = (const float*)d_in[6];
    const float* b2 = (const float*)d_in[7];
    float* out = (float*)d_out;

    int N = in_sizes[0] / 128;
    int E = in_sizes[1] / 2;
    const int* src = eidx;
    const int* dst = eidx + E;
    int nbuck = (N + 255) >> 8;
    int ntile = (E + 4095) / 4096;

    char* ws = (char*)d_ws;
    size_t off = 0;
    auto alloc = [&](size_t bytes) -> void* {
        void* p = ws + off;
        off += (bytes + 255) & ~(size_t)255;
        return p;
    };
    float*  dinv    = (float*)alloc((size_t)N * 4);
    int*    rowptr  = (int*)alloc(((size_t)N + 1) * 4);
    int*    csr     = (int*)alloc((size_t)E * 4);
    uint*   pairbuf = (uint*)alloc((size_t)E * 4);
    int*    bcnt    = (int*)alloc(512 * 4);
    int*    bbase   = (int*)alloc(513 * 4);
    int*    bcur    = (int*)alloc(512 * 4);
    ushort* w1t     = (ushort*)alloc(128 * 128 * 2);
    ushort* wmt     = (ushort*)alloc(128 * 128 * 2);
    ushort* w2t     = (ushort*)alloc(48 * 128 * 2);
    ushort* gbuf    = (ushort*)alloc((size_t)N * 128 * 2);  // g1, UNSCALED
    ushort* hbuf    = (ushort*)alloc((size_t)N * 128 * 2);  // h1/h2 plain
    ushort* gbuf2   = (ushort*)alloc((size_t)N * 128 * 2);  // g2, pre-scaled
    ushort* g3      = (ushort*)alloc((size_t)N * 40 * 2);   // g3, pre-scaled

    int gblk64 = (N + 63) / 64;
    int gblk16 = (N + 15) / 16;

    hipMemsetAsync(bcnt, 0, 512 * 4, stream);
    // castT (152 blocks) || bhist (ntile blocks)
    k_pre1<<<152 + ntile, 256, 0, stream>>>(W1, Wm, W2, w1t, wmt, w2t, dst, bcnt, E);
    k_bscan<<<1, 512, 0, stream>>>(bcnt, bbase, bcur, nbuck);
    // binpack (ntile) || gemm1 (gblk64, unscaled out)
    k_pack_gemm<<<ntile + gblk64, 256, 0, stream>>>(src, dst, bcur, pairbuf, E, nbuck,
                                                    ntile, x, w1t, gbuf, N);
    k_csrbuild<<<nbuck, 256, 0, stream>>>(pairbuf, bbase, rowptr, dinv, csr, N, nbuck);
    // layer 1 agg (per-edge dinv) -> h1 plain
    k_aggA<<<gblk16, 256, 0, stream>>>(gbuf, dinv, rowptr, csr, b1, hbuf, N);
    // layer 2 GEMM -> g2 pre-scaled
    k_gemm128s<<<gblk64, 256, 0, stream>>>(hbuf, wmt, dinv, gbuf2, N);
    // layer 2 agg (plain adds) -> h2 plain
    k_aggB<<<gblk16, 256, 0, stream>>>(gbuf2, dinv, rowptr, csr, bm, hbuf, N);
    // layer 3 GEMM -> g3 pre-scaled (40 cols)
    k_gemm40s<<<gblk64, 256, 0, stream>>>(hbuf, w2t, dinv, g3, N);
    // final aggregation
    k_agg40_b<<<(N + 24) / 25, 256, 0, stream>>>(g3, dinv, rowptr, csr, b2, out, N);
}